// Round 1
// baseline (423.902 us; speedup 1.0000x reference)
//
#include <hip/hip_runtime.h>

// KV cache update, token-gen path.
// Shapes: L=2, B=4, H=8, M=4096, D=128, fp32.
// out[2, L, B, H, M, D]: out[0]=k_caches, out[1]=v_caches, with row
// m == position_ids[b] replaced by latest_{k,v}[l,b,h,0,:] for every (l,b,h).
// Pure streaming copy (537 MB HBM traffic) + 64-row sparse overwrite, fused.

constexpr int Ln = 2, Bn = 4, Hn = 8, Mn = 4096, Dn = 128;
constexpr long N_ELEM  = (long)Ln * Bn * Hn * Mn * Dn;   // 33,554,432 per cache
constexpr long N_VEC   = N_ELEM / 4;                     // 8,388,608 float4 per cache
constexpr long TOT_VEC = 2 * N_VEC;                      // 16,777,216 float4 total

__global__ __launch_bounds__(256) void kv_update_kernel(
    const float4* __restrict__ kc,   // k_caches
    const float4* __restrict__ vc,   // v_caches
    const float4* __restrict__ lk,   // latest_k
    const float4* __restrict__ lv,   // latest_v
    const int*    __restrict__ pos,  // position_ids (B,1)
    float4*       __restrict__ out)
{
    long i = (long)blockIdx.x * 256 + threadIdx.x;   // grid exactly covers TOT_VEC

    // Flat vec index decode (all dims pow2 -> shifts/masks only):
    // i = (((((kv*L + l)*B + b)*H + h)*M + m) * (D/4)) + lane
    int  lane = (int)(i & 31);          // D/4 = 32
    long t    = i >> 5;
    int  m    = (int)(t & (Mn - 1));    // M = 4096
    long t2   = t >> 12;
    int  h    = (int)(t2 & (Hn - 1));   // H = 8
    long t3   = t2 >> 3;
    int  b    = (int)(t3 & (Bn - 1));   // B = 4
    long t4   = t3 >> 2;
    int  l    = (int)(t4 & 1);          // L = 2
    int  kv   = (int)(t4 >> 1);         // 0 = k, 1 = v

    // Streaming copy: source cache, same offset within its half.
    const float4* src = kv ? vc : kc;
    float4 val = src[i & (N_VEC - 1)];

    // Sparse overwrite: b is wave-uniform -> pos[b] is a scalar (L1) load.
    int p = pos[b];
    if (m == p) {
        const float4* lsrc = kv ? lv : lk;
        val = lsrc[((l * Bn + b) * Hn + h) * (Dn / 4) + lane];
    }

    out[i] = val;
}

extern "C" void kernel_launch(void* const* d_in, const int* in_sizes, int n_in,
                              void* d_out, int out_size, void* d_ws, size_t ws_size,
                              hipStream_t stream) {
    const float4* kc  = (const float4*)d_in[0];
    const float4* vc  = (const float4*)d_in[1];
    const float4* lk  = (const float4*)d_in[2];
    const float4* lv  = (const float4*)d_in[3];
    const int*    pos = (const int*)d_in[4];
    // d_in[5] = seq_len (unused: position_ids < seq_len by construction,
    // and the scatter+concat is equivalent to a direct row overwrite).
    float4* out = (float4*)d_out;

    const int block = 256;
    const long grid = TOT_VEC / block;   // 65,536 blocks, exact cover
    kv_update_kernel<<<(dim3)(unsigned)grid, block, 0, stream>>>(kc, vc, lk, lv, pos, out);
}